// Round 2
// baseline (404.381 us; speedup 1.0000x reference)
//
#include <hip/hip_runtime.h>

// AttentionBlock: x[4,64,64,256] f32; q=x@Wq+bq (d=32), k=x@Wk+bk, v=x@Wv+bv (256)
// scores=q@k^T (no 1/sqrt(d)), softmax, out = gamma*(attn@v) + x.
// Strategy: bf16 MFMA everywhere. ws layout:
//   Qb  bf16 [4][4096][32]   @ 0       (1 MiB)
//   Kb  bf16 [4][4096][32]   @ 1 MiB   (1 MiB)
//   Vt  bf16 [4][256][4096]  @ 2 MiB   (8 MiB)  (V transposed for PV B-frags)
//   Wt  bf16 [320][256]      @ 10 MiB  (160 KiB) (W^T: q cols 0-31, k 32-63, v 64-319)
//   Wlo bf16 [64][256]       @ 10 MiB+256K (32 KiB) (bf16 residual, q/k cols only)
//   bcat f32 [320]           @ 10 MiB+320K
// Total < 11 MiB of ws.

using short8 = __attribute__((ext_vector_type(8))) short;
using f32x4  = __attribute__((ext_vector_type(4))) float;

#define MFMA(a,b,c) __builtin_amdgcn_mfma_f32_16x16x32_bf16((a),(b),(c),0,0,0)

__device__ __forceinline__ unsigned short f2bf(float f) {
  union { float f; unsigned int u; } a; a.f = f;
  unsigned int u = a.u;
  return (unsigned short)((u + 0x7fffu + ((u >> 16) & 1u)) >> 16);  // RNE
}
__device__ __forceinline__ float bf2f(unsigned short h) {
  union { unsigned int u; float f; } a; a.u = ((unsigned int)h) << 16;
  return a.f;
}

// ---------------- pack W (transpose to bf16, + lo residual for q/k) ----------
__global__ __launch_bounds__(64) void pack_w_kernel(
    const float* __restrict__ Wq, const float* __restrict__ bq,
    const float* __restrict__ Wk, const float* __restrict__ bk,
    const float* __restrict__ Wv, const float* __restrict__ bv,
    unsigned short* __restrict__ Wt, unsigned short* __restrict__ Wlo,
    float* __restrict__ bcat)
{
  const int c = blockIdx.x;   // 0..319 packed output column
  const int t = threadIdx.x;  // 0..63
  const float* W; int cc, stride;
  if (c < 32)      { W = Wq; cc = c;      stride = 32;  }
  else if (c < 64) { W = Wk; cc = c - 32; stride = 32;  }
  else             { W = Wv; cc = c - 64; stride = 256; }
  for (int k = t; k < 256; k += 64) {
    float w = W[(size_t)k * stride + cc];
    unsigned short hi = f2bf(w);
    Wt[(size_t)c * 256 + k] = hi;
    if (c < 64) Wlo[(size_t)c * 256 + k] = f2bf(w - bf2f(hi));
  }
  if (t == 0)
    bcat[c] = (c < 32) ? bq[c] : (c < 64) ? bk[c - 32] : bv[c - 64];
}

// ---------------- fused QKV projection GEMM [16384,256]@[256,320] -----------
// 1 wave per block; block computes 16 rows x 320 cols. K=256 = 8 MFMA steps.
// q/k columns (ct<4) use split-bf16 (hi/lo) for near-fp32 accuracy.
__global__ __launch_bounds__(64) void qkv_kernel(
    const float* __restrict__ x,
    const unsigned short* __restrict__ Wt,
    const unsigned short* __restrict__ Wlo,
    const float* __restrict__ bcat,
    unsigned short* __restrict__ Qb, unsigned short* __restrict__ Kb,
    unsigned short* __restrict__ Vt)
{
  const int l = threadIdx.x, lr = l & 15, lg = l >> 4;
  const int row0 = blockIdx.x * 16;   // global row in [0, 16384)

  // A fragments: lane holds x[row0+lr][ks*32 + lg*8 + j], hi/lo bf16 split
  short8 ahi[8], alo[8];
  const float* xr = x + (size_t)(row0 + lr) * 256 + lg * 8;
  #pragma unroll
  for (int ks = 0; ks < 8; ++ks) {
    short8 h, lo2;
    #pragma unroll
    for (int j = 0; j < 8; ++j) {
      float v = xr[ks * 32 + j];
      unsigned short hh = f2bf(v);
      h[j]   = (short)hh;
      lo2[j] = (short)f2bf(v - bf2f(hh));
    }
    ahi[ks] = h; alo[ks] = lo2;
  }

  f32x4 acc[20];
  #pragma unroll
  for (int i = 0; i < 20; ++i) acc[i] = (f32x4){0.f, 0.f, 0.f, 0.f};

  #pragma unroll
  for (int ct = 0; ct < 20; ++ct) {
    const unsigned short* wrow = Wt + (size_t)(ct * 16 + lr) * 256 + lg * 8;
    #pragma unroll
    for (int ks = 0; ks < 8; ++ks) {
      short8 bh = *(const short8*)(wrow + ks * 32);
      acc[ct] = MFMA(ahi[ks], bh, acc[ct]);
      if (ct < 4) {  // q/k columns: split-precision
        short8 bl = *(const short8*)(Wlo + (size_t)(ct * 16 + lr) * 256 + ks * 32 + lg * 8);
        acc[ct] = MFMA(alo[ks], bh, acc[ct]);
        acc[ct] = MFMA(ahi[ks], bl, acc[ct]);
      }
    }
  }

  const int b = row0 >> 12, n0 = row0 & 4095;
  #pragma unroll
  for (int ct = 0; ct < 20; ++ct) {
    const int col = ct * 16 + lr;
    const float bias = bcat[col];
    #pragma unroll
    for (int r = 0; r < 4; ++r) {
      const int row = lg * 4 + r;   // D layout: row=(l>>4)*4+r, col=l&15
      unsigned short h = f2bf(acc[ct][r] + bias);
      if (col < 32)      Qb[(size_t)(row0 + row) * 32 + col] = h;
      else if (col < 64) Kb[(size_t)(row0 + row) * 32 + (col - 32)] = h;
      else               Vt[((size_t)b * 256 + (col - 64)) * 4096 + n0 + row] = h;
    }
  }
}

// ---------------- flash attention: 1 wave = 16 q-rows ------------------------
__global__ __launch_bounds__(64) void attn_kernel(
    const unsigned short* __restrict__ Qb,
    const unsigned short* __restrict__ Kb,
    const unsigned short* __restrict__ Vt,
    const float* __restrict__ x,
    const float* __restrict__ gamma_p,
    float* __restrict__ out)
{
  const int l = threadIdx.x, lr = l & 15, lg = l >> 4;
  const int bid = blockIdx.x;
  const int b  = bid >> 8;          // 256 row-tiles per batch
  const int n0 = (bid & 255) << 4;  // q-row base

  // Q fragment lives in registers for the whole kernel (d_qk = 32 = one K-step)
  const short8 qf = *(const short8*)(Qb + (size_t)(b * 4096 + n0 + lr) * 32 + lg * 8);

  f32x4 O[16];
  #pragma unroll
  for (int i = 0; i < 16; ++i) O[i] = (f32x4){0.f, 0.f, 0.f, 0.f};
  float m[4]    = {-1e30f, -1e30f, -1e30f, -1e30f};
  float lsum[4] = {0.f, 0.f, 0.f, 0.f};

  // P bounce buffer: stride 40 ushorts (80B) keeps 16B alignment for b128 reads
  // and makes the frag read 2-lanes-per-bank (free).
  __shared__ __align__(16) unsigned short Plds[16][40];

  const unsigned short* Kbase = Kb + (size_t)b * 4096 * 32;
  const unsigned short* Vbase = Vt + (size_t)b * 256 * 4096;

  for (int kv = 0; kv < 4096; kv += 32) {
    // S = Q @ K^T : two 16x16 kv sub-tiles, each one MFMA
    short8 kf0 = *(const short8*)(Kbase + (size_t)(kv + lr) * 32 + lg * 8);
    short8 kf1 = *(const short8*)(Kbase + (size_t)(kv + 16 + lr) * 32 + lg * 8);
    f32x4 z = (f32x4){0.f, 0.f, 0.f, 0.f};
    f32x4 S0 = MFMA(qf, kf0, z);   // lane: S[q-row lg*4+r][kv + lr]
    f32x4 S1 = MFMA(qf, kf1, z);   // lane: S[q-row lg*4+r][kv + 16 + lr]

    // per-row max over the 32 kv positions (reduce across the 16 lanes of lg-group)
    float mx[4];
    #pragma unroll
    for (int r = 0; r < 4; ++r) {
      float v = fmaxf(S0[r], S1[r]);
      v = fmaxf(v, __shfl_xor(v, 1, 16));
      v = fmaxf(v, __shfl_xor(v, 2, 16));
      v = fmaxf(v, __shfl_xor(v, 4, 16));
      v = fmaxf(v, __shfl_xor(v, 8, 16));
      mx[r] = v;
    }

    // T13 defer-max: only rescale when the running max grew by > 8
    bool upd = (mx[0] > m[0] + 8.f) || (mx[1] > m[1] + 8.f) ||
               (mx[2] > m[2] + 8.f) || (mx[3] > m[3] + 8.f);
    if (__any((int)upd)) {
      float sc[4];
      #pragma unroll
      for (int r = 0; r < 4; ++r) {
        float mn = fmaxf(m[r], mx[r]);
        sc[r] = __expf(m[r] - mn);   // exp(-1e30-..)=0 handles first tile
        m[r] = mn;
        lsum[r] *= sc[r];
      }
      #pragma unroll
      for (int i = 0; i < 16; ++i) {
        #pragma unroll
        for (int r = 0; r < 4; ++r) O[i][r] *= sc[r];
      }
    }

    // P = exp(S - m) (bounded by e^8 when deferred), accumulate row sums
    #pragma unroll
    for (int r = 0; r < 4; ++r) {
      S0[r] = __expf(S0[r] - m[r]);
      S1[r] = __expf(S1[r] - m[r]);
      float s = S0[r] + S1[r];
      s += __shfl_xor(s, 1, 16);
      s += __shfl_xor(s, 2, 16);
      s += __shfl_xor(s, 4, 16);
      s += __shfl_xor(s, 8, 16);
      lsum[r] += s;
    }

    // bounce P through LDS into the PV A-fragment layout
    __syncthreads();
    #pragma unroll
    for (int r = 0; r < 4; ++r) {
      Plds[lg * 4 + r][lr]      = f2bf(S0[r]);
      Plds[lg * 4 + r][16 + lr] = f2bf(S1[r]);
    }
    __syncthreads();
    const short8 pf = *(const short8*)&Plds[lr][lg * 8];  // P[q-row lr][k lg*8+j]

    // O += P @ V : 16 col-tiles of 16, V read transposed (contiguous 16B/lane)
    #pragma unroll
    for (int ct = 0; ct < 16; ++ct) {
      short8 vf = *(const short8*)(Vbase + (size_t)(ct * 16 + lr) * 4096 + kv + lg * 8);
      O[ct] = MFMA(pf, vf, O[ct]);
    }
  }

  const float g = gamma_p[0];
  float rl[4];
  #pragma unroll
  for (int r = 0; r < 4; ++r) rl[r] = 1.f / lsum[r];
  #pragma unroll
  for (int ct = 0; ct < 16; ++ct) {
    #pragma unroll
    for (int r = 0; r < 4; ++r) {
      const size_t idx = ((size_t)(b * 4096 + n0 + lg * 4 + r)) * 256 + ct * 16 + lr;
      out[idx] = g * (O[ct][r] * rl[r]) + x[idx];
    }
  }
}

extern "C" void kernel_launch(void* const* d_in, const int* in_sizes, int n_in,
                              void* d_out, int out_size, void* d_ws, size_t ws_size,
                              hipStream_t stream)
{
  const float* x     = (const float*)d_in[0];
  const float* Wq    = (const float*)d_in[1];
  const float* bq    = (const float*)d_in[2];
  const float* Wk    = (const float*)d_in[3];
  const float* bk    = (const float*)d_in[4];
  const float* Wv    = (const float*)d_in[5];
  const float* bv    = (const float*)d_in[6];
  const float* gamma = (const float*)d_in[7];
  float* out = (float*)d_out;

  char* ws = (char*)d_ws;
  unsigned short* Qb  = (unsigned short*)(ws);
  unsigned short* Kb  = (unsigned short*)(ws + (1u << 20));
  unsigned short* Vt  = (unsigned short*)(ws + (2u << 20));
  unsigned short* Wt  = (unsigned short*)(ws + (10u << 20));
  unsigned short* Wlo = (unsigned short*)(ws + (10u << 20) + (256u << 10));
  float*          bcat = (float*)(ws + (10u << 20) + (320u << 10));

  pack_w_kernel<<<dim3(320), dim3(64), 0, stream>>>(Wq, bq, Wk, bk, Wv, bv, Wt, Wlo, bcat);
  qkv_kernel<<<dim3(1024), dim3(64), 0, stream>>>(x, Wt, Wlo, bcat, Qb, Kb, Vt);
  attn_kernel<<<dim3(1024), dim3(64), 0, stream>>>(Qb, Kb, Vt, x, gamma, out);
}

// Round 3
// 367.900 us; speedup vs baseline: 1.0992x; 1.0992x over previous
//
#include <hip/hip_runtime.h>

// AttentionBlock: x[4,64,64,256] f32; q=x@Wq+bq (d=32), k=x@Wk+bk, v=x@Wv+bv (256)
// scores=q@k^T (no 1/sqrt(d)), softmax, out = gamma*(attn@v) + x.
// ws layout:
//   Qb  bf16 [4][4096][32]   @ 0       ; Kb @ 1MiB ; Vt bf16 [4][256][4096] @ 2MiB
//   Wt  bf16 [320][256] @ 10MiB ; Wlo bf16 [64][256] @ +256K ; bcat f32[320] @ +320K

using short8 = __attribute__((ext_vector_type(8))) short;
using f32x4  = __attribute__((ext_vector_type(4))) float;

#define MFMA(a,b,c) __builtin_amdgcn_mfma_f32_16x16x32_bf16((a),(b),(c),0,0,0)

__device__ __forceinline__ unsigned short f2bf(float f) {
  union { float f; unsigned int u; } a; a.f = f;
  unsigned int u = a.u;
  return (unsigned short)((u + 0x7fffu + ((u >> 16) & 1u)) >> 16);  // RNE
}
__device__ __forceinline__ float bf2f(unsigned short h) {
  union { unsigned int u; float f; } a; a.u = ((unsigned int)h) << 16;
  return a.f;
}

// ---------------- pack W (transpose to bf16, + lo residual for q/k) ----------
__global__ __launch_bounds__(64) void pack_w_kernel(
    const float* __restrict__ Wq, const float* __restrict__ bq,
    const float* __restrict__ Wk, const float* __restrict__ bk,
    const float* __restrict__ Wv, const float* __restrict__ bv,
    unsigned short* __restrict__ Wt, unsigned short* __restrict__ Wlo,
    float* __restrict__ bcat)
{
  const int c = blockIdx.x;   // 0..319 packed output column
  const int t = threadIdx.x;  // 0..63
  const float* W; int cc, stride;
  if (c < 32)      { W = Wq; cc = c;      stride = 32;  }
  else if (c < 64) { W = Wk; cc = c - 32; stride = 32;  }
  else             { W = Wv; cc = c - 64; stride = 256; }
  for (int k = t; k < 256; k += 64) {
    float w = W[(size_t)k * stride + cc];
    unsigned short hi = f2bf(w);
    Wt[(size_t)c * 256 + k] = hi;
    if (c < 64) Wlo[(size_t)c * 256 + k] = f2bf(w - bf2f(hi));
  }
  if (t == 0)
    bcat[c] = (c < 32) ? bq[c] : (c < 64) ? bk[c - 32] : bv[c - 64];
}

// ---------------- fused QKV projection GEMM [16384,256]@[256,320] -----------
// 4 waves/block, 16 rows/block; wave w owns ct tiles {w, w+4, w+8, w+12, w+16}
// (exactly one split-precision q/k tile each). 4 waves/SIMD occupancy.
__global__ __launch_bounds__(256, 4) void qkv_kernel(
    const float* __restrict__ x,
    const unsigned short* __restrict__ Wt,
    const unsigned short* __restrict__ Wlo,
    const float* __restrict__ bcat,
    unsigned short* __restrict__ Qb, unsigned short* __restrict__ Kb,
    unsigned short* __restrict__ Vt)
{
  const int tid = threadIdx.x, wid = tid >> 6;
  const int l = tid & 63, lr = l & 15, lg = l >> 4;
  const int row0 = blockIdx.x * 16;   // global row in [0, 16384)

  // A fragments: lane holds x[row0+lr][ks*32 + lg*8 + j], hi/lo bf16 split
  short8 ahi[8], alo[8];
  const float* xr = x + (size_t)(row0 + lr) * 256 + lg * 8;
  #pragma unroll
  for (int ks = 0; ks < 8; ++ks) {
    short8 h, lo2;
    #pragma unroll
    for (int j = 0; j < 8; ++j) {
      float v = xr[ks * 32 + j];
      unsigned short hh = f2bf(v);
      h[j]   = (short)hh;
      lo2[j] = (short)f2bf(v - bf2f(hh));
    }
    ahi[ks] = h; alo[ks] = lo2;
  }

  const int bb = row0 >> 12, n0 = row0 & 4095;
  #pragma unroll
  for (int i = 0; i < 5; ++i) {
    const int ct = wid + i * 4;
    f32x4 acc = (f32x4){0.f, 0.f, 0.f, 0.f};
    const unsigned short* wrow = Wt + (size_t)(ct * 16 + lr) * 256 + lg * 8;
    #pragma unroll
    for (int ks = 0; ks < 8; ++ks) {
      short8 bh = *(const short8*)(wrow + ks * 32);
      acc = MFMA(ahi[ks], bh, acc);
    }
    if (i == 0) {  // ct = wid < 4: q/k columns, split-bf16 precision
      const unsigned short* lrow = Wlo + (size_t)(ct * 16 + lr) * 256 + lg * 8;
      #pragma unroll
      for (int ks = 0; ks < 8; ++ks) {
        short8 bh = *(const short8*)(wrow + ks * 32);
        short8 bl = *(const short8*)(lrow + ks * 32);
        acc = MFMA(alo[ks], bh, acc);
        acc = MFMA(ahi[ks], bl, acc);
      }
    }
    const int col = ct * 16 + lr;
    const float bias = bcat[col];
    #pragma unroll
    for (int r = 0; r < 4; ++r) {
      const int row = lg * 4 + r;   // D layout: row=(l>>4)*4+r, col=l&15
      unsigned short h = f2bf(acc[r] + bias);
      if (col < 32)      Qb[(size_t)(row0 + row) * 32 + col] = h;
      else if (col < 64) Kb[(size_t)(row0 + row) * 32 + (col - 32)] = h;
      else               Vt[((size_t)bb * 256 + (col - 64)) * 4096 + n0 + row] = h;
    }
  }
}

// ---------------- flash attention: block = 4 waves, 16 q-rows, split-KV ------
// wave w covers kv in [w*1024, (w+1)*1024); LDS online-softmax merge at end.
__global__ __launch_bounds__(256, 4) void attn_kernel(
    const unsigned short* __restrict__ Qb,
    const unsigned short* __restrict__ Kb,
    const unsigned short* __restrict__ Vt,
    const float* __restrict__ x,
    const float* __restrict__ gamma_p,
    float* __restrict__ out)
{
  const int tid = threadIdx.x, wid = tid >> 6;
  const int l = tid & 63, lr = l & 15, lg = l >> 4;

  // XCD swizzle (assumes round-robin bid%8 -> XCD): batch b on XCDs {2b,2b+1}
  // so each XCD's L2 holds one batch's Vt(2MB)+Kb+Qb (<4MiB). Bijective.
  const int bid = blockIdx.x;
  const int b  = (bid & 7) >> 1;
  const int t  = (bid >> 3) * 2 + (bid & 1);
  const int n0 = t << 4;

  __shared__ float Osh[16][260];                       // padded: 2-way-free banks
  __shared__ float msh[4][16];
  __shared__ float lsh[4][16];
  __shared__ __align__(16) unsigned short Plds[4][16][40];  // per-wave P bounce

  const unsigned short* Kbase = Kb + (size_t)b * 4096 * 32;
  const unsigned short* Vbase = Vt + (size_t)b * 256 * 4096;

  // Q fragment in registers for the whole kernel (d_qk = 32 = one K-step)
  const short8 qf = *(const short8*)(Qb + (size_t)(b * 4096 + n0 + lr) * 32 + lg * 8);

  f32x4 O[16];
  #pragma unroll
  for (int i = 0; i < 16; ++i) O[i] = (f32x4){0.f, 0.f, 0.f, 0.f};
  float m[4]    = {-1e30f, -1e30f, -1e30f, -1e30f};
  float lsum[4] = {0.f, 0.f, 0.f, 0.f};

  const int kv0 = wid << 10;
  for (int kv = kv0; kv < kv0 + 1024; kv += 32) {
    // S = Q @ K^T : two 16x16 kv sub-tiles
    short8 kf0 = *(const short8*)(Kbase + (size_t)(kv + lr) * 32 + lg * 8);
    short8 kf1 = *(const short8*)(Kbase + (size_t)(kv + 16 + lr) * 32 + lg * 8);
    f32x4 z = (f32x4){0.f, 0.f, 0.f, 0.f};
    f32x4 S0 = MFMA(qf, kf0, z);   // lane: S[q-row lg*4+r][kv + lr]
    f32x4 S1 = MFMA(qf, kf1, z);

    // per-row max over the 32 kv positions
    float mx[4];
    #pragma unroll
    for (int r = 0; r < 4; ++r) {
      float v = fmaxf(S0[r], S1[r]);
      v = fmaxf(v, __shfl_xor(v, 1, 16));
      v = fmaxf(v, __shfl_xor(v, 2, 16));
      v = fmaxf(v, __shfl_xor(v, 4, 16));
      v = fmaxf(v, __shfl_xor(v, 8, 16));
      mx[r] = v;
    }

    // T13 defer-max: rescale only when max grew by > 8
    bool upd = (mx[0] > m[0] + 8.f) || (mx[1] > m[1] + 8.f) ||
               (mx[2] > m[2] + 8.f) || (mx[3] > m[3] + 8.f);
    if (__any((int)upd)) {
      float sc[4];
      #pragma unroll
      for (int r = 0; r < 4; ++r) {
        float mn = fmaxf(m[r], mx[r]);
        sc[r] = __expf(m[r] - mn);   // exp(-1e30-..)=0 handles first tile
        m[r] = mn;
        lsum[r] *= sc[r];
      }
      #pragma unroll
      for (int i = 0; i < 16; ++i) {
        #pragma unroll
        for (int r = 0; r < 4; ++r) O[i][r] *= sc[r];
      }
    }

    // P = exp(S - m), row sums
    #pragma unroll
    for (int r = 0; r < 4; ++r) {
      S0[r] = __expf(S0[r] - m[r]);
      S1[r] = __expf(S1[r] - m[r]);
      float s = S0[r] + S1[r];
      s += __shfl_xor(s, 1, 16);
      s += __shfl_xor(s, 2, 16);
      s += __shfl_xor(s, 4, 16);
      s += __shfl_xor(s, 8, 16);
      lsum[r] += s;
    }

    // bounce P through per-wave LDS region (wave-local sync only: in-order DS
    // pipe; lgkmcnt(0) + memory clobber stops any reordering)
    #pragma unroll
    for (int r = 0; r < 4; ++r) {
      Plds[wid][lg * 4 + r][lr]      = f2bf(S0[r]);
      Plds[wid][lg * 4 + r][16 + lr] = f2bf(S1[r]);
    }
    asm volatile("s_waitcnt lgkmcnt(0)" ::: "memory");
    const short8 pf = *(const short8*)&Plds[wid][lr][lg * 8];

    // O += P @ V : V read transposed (contiguous 16B/lane), L2-resident
    #pragma unroll
    for (int ct = 0; ct < 16; ++ct) {
      short8 vf = *(const short8*)(Vbase + (size_t)(ct * 16 + lr) * 4096 + kv + lg * 8);
      O[ct] = MFMA(pf, vf, O[ct]);
    }
  }

  // ---- cross-wave online-softmax merge in LDS ----
  if (lr == 0) {
    #pragma unroll
    for (int r = 0; r < 4; ++r) msh[wid][lg * 4 + r] = m[r];
  }
  __syncthreads();
  float sw[4];
  #pragma unroll
  for (int r = 0; r < 4; ++r) {
    const int row = lg * 4 + r;
    float M = fmaxf(fmaxf(msh[0][row], msh[1][row]),
                    fmaxf(msh[2][row], msh[3][row]));
    sw[r] = __expf(m[r] - M);
    lsum[r] *= sw[r];
  }
  if (lr == 0) {
    #pragma unroll
    for (int r = 0; r < 4; ++r) lsh[wid][lg * 4 + r] = lsum[r];
  }
  #pragma unroll
  for (int w = 0; w < 4; ++w) {
    __syncthreads();
    if (wid == w) {
      #pragma unroll
      for (int ct = 0; ct < 16; ++ct) {
        #pragma unroll
        for (int r = 0; r < 4; ++r) {
          float v = sw[r] * O[ct][r];
          float* p = &Osh[lg * 4 + r][ct * 16 + lr];
          if (w == 0) *p = v; else *p += v;
        }
      }
    }
  }
  __syncthreads();

  // ---- epilogue: out = gamma*(Osh/L) + x, coalesced float4 ----
  const float g = gamma_p[0];
  const int erow0 = (tid >> 6) * 4;
  const int col = (tid & 63) * 4;
  #pragma unroll
  for (int i = 0; i < 4; ++i) {
    const int row = erow0 + i;
    const float L = lsh[0][row] + lsh[1][row] + lsh[2][row] + lsh[3][row];
    const float s = g / L;
    const size_t idx = (size_t)(b * 4096 + n0 + row) * 256 + col;
    f32x4 o  = *(const f32x4*)&Osh[row][col];
    f32x4 xi = *(const f32x4*)(x + idx);
    f32x4 res;
    #pragma unroll
    for (int j = 0; j < 4; ++j) res[j] = o[j] * s + xi[j];
    *(f32x4*)(out + idx) = res;
  }
}

extern "C" void kernel_launch(void* const* d_in, const int* in_sizes, int n_in,
                              void* d_out, int out_size, void* d_ws, size_t ws_size,
                              hipStream_t stream)
{
  const float* x     = (const float*)d_in[0];
  const float* Wq    = (const float*)d_in[1];
  const float* bq    = (const float*)d_in[2];
  const float* Wk    = (const float*)d_in[3];
  const float* bk    = (const float*)d_in[4];
  const float* Wv    = (const float*)d_in[5];
  const float* bv    = (const float*)d_in[6];
  const float* gamma = (const float*)d_in[7];
  float* out = (float*)d_out;

  char* ws = (char*)d_ws;
  unsigned short* Qb  = (unsigned short*)(ws);
  unsigned short* Kb  = (unsigned short*)(ws + (1u << 20));
  unsigned short* Vt  = (unsigned short*)(ws + (2u << 20));
  unsigned short* Wt  = (unsigned short*)(ws + (10u << 20));
  unsigned short* Wlo = (unsigned short*)(ws + (10u << 20) + (256u << 10));
  float*          bcat = (float*)(ws + (10u << 20) + (320u << 10));

  pack_w_kernel<<<dim3(320), dim3(64), 0, stream>>>(Wq, bq, Wk, bk, Wv, bv, Wt, Wlo, bcat);
  qkv_kernel<<<dim3(1024), dim3(256), 0, stream>>>(x, Wt, Wlo, bcat, Qb, Kb, Vt);
  attn_kernel<<<dim3(1024), dim3(256), 0, stream>>>(Qb, Kb, Vt, x, gamma, out);
}

// Round 8
// 260.459 us; speedup vs baseline: 1.5526x; 1.4125x over previous
//
#include <hip/hip_runtime.h>

// AttentionBlock: x[4,64,64,256] f32; q=x@Wq+bq (d=32), k=x@Wk+bk, v=x@Wv+bv (256)
// scores=q@k^T (no 1/sqrt(d)), softmax, out = gamma*(attn@v) + x.
// ws layout:
//   Qb  bf16 [4][4096][32]   @ 0       ; Kb @ 1MiB ; Vt bf16 [4][256][4096] @ 2MiB
//   Wt  bf16 [320][256] @ 10MiB ; Wlo bf16 [64][256] @ +256K ; bcat f32[320] @ +320K

using short8 = __attribute__((ext_vector_type(8))) short;
using f32x4  = __attribute__((ext_vector_type(4))) float;
using f32x16 = __attribute__((ext_vector_type(16))) float;
using int4v  = __attribute__((ext_vector_type(4))) int;

#define MFMA16(a,b,c) __builtin_amdgcn_mfma_f32_16x16x32_bf16((a),(b),(c),0,0,0)
#define MFMA32(a,b,c) __builtin_amdgcn_mfma_f32_32x32x16_bf16((a),(b),(c),0,0,0)

__device__ __forceinline__ unsigned short f2bf(float f) {
  union { float f; unsigned int u; } a; a.f = f;
  unsigned int u = a.u;
  return (unsigned short)((u + 0x7fffu + ((u >> 16) & 1u)) >> 16);  // RNE
}
__device__ __forceinline__ float bf2f(unsigned short h) {
  union { unsigned int u; float f; } a; a.u = ((unsigned int)h) << 16;
  return a.f;
}
// dst.lo16 = bf16(lo), dst.hi16 = bf16(hi)  [m240-verified gfx950 instr]
__device__ __forceinline__ unsigned int cvtpk(float lo, float hi) {
  unsigned int r;
  asm("v_cvt_pk_bf16_f32 %0, %1, %2" : "=v"(r) : "v"(lo), "v"(hi));
  return r;
}
// cross-half (lane ^ 32) combine via known-good shfl (ds_bpermute path)
__device__ __forceinline__ float xhalf_max(float v) {
  return fmaxf(v, __shfl_xor(v, 32));
}
__device__ __forceinline__ float xhalf_add(float v) {
  return v + __shfl_xor(v, 32);
}

// ---------------- pack W (transpose to bf16, + lo residual for q/k) ----------
__global__ __launch_bounds__(64) void pack_w_kernel(
    const float* __restrict__ Wq, const float* __restrict__ bq,
    const float* __restrict__ Wk, const float* __restrict__ bk,
    const float* __restrict__ Wv, const float* __restrict__ bv,
    unsigned short* __restrict__ Wt, unsigned short* __restrict__ Wlo,
    float* __restrict__ bcat)
{
  const int c = blockIdx.x;   // 0..319 packed output column
  const int t = threadIdx.x;  // 0..63
  const float* W; int cc, stride;
  if (c < 32)      { W = Wq; cc = c;      stride = 32;  }
  else if (c < 64) { W = Wk; cc = c - 32; stride = 32;  }
  else             { W = Wv; cc = c - 64; stride = 256; }
  for (int k = t; k < 256; k += 64) {
    float w = W[(size_t)k * stride + cc];
    unsigned short hi = f2bf(w);
    Wt[(size_t)c * 256 + k] = hi;
    if (c < 64) Wlo[(size_t)c * 256 + k] = f2bf(w - bf2f(hi));
  }
  if (t == 0)
    bcat[c] = (c < 32) ? bq[c] : (c < 64) ? bk[c - 32] : bv[c - 64];
}

// ---------------- fused QKV projection GEMM [16384,256]@[256,320] -----------
// 4 waves/block, 16 rows/block; wave w owns ct tiles {w, w+4, w+8, w+12, w+16}
__global__ __launch_bounds__(256, 4) void qkv_kernel(
    const float* __restrict__ x,
    const unsigned short* __restrict__ Wt,
    const unsigned short* __restrict__ Wlo,
    const float* __restrict__ bcat,
    unsigned short* __restrict__ Qb, unsigned short* __restrict__ Kb,
    unsigned short* __restrict__ Vt)
{
  const int tid = threadIdx.x, wid = tid >> 6;
  const int l = tid & 63, lr = l & 15, lg = l >> 4;
  const int row0 = blockIdx.x * 16;   // global row in [0, 16384)

  // A fragments: lane holds x[row0+lr][ks*32 + lg*8 + j], hi/lo bf16 split.
  short8 ahi[8], alo[8];
  const float* xr = x + (size_t)(row0 + lr) * 256 + lg * 8;
  #pragma unroll
  for (int ks = 0; ks < 8; ++ks) {
    f32x4 v0 = *(const f32x4*)(xr + ks * 32);
    f32x4 v1 = *(const f32x4*)(xr + ks * 32 + 4);
    short8 h, lo2;
    #pragma unroll
    for (int j = 0; j < 4; ++j) {
      unsigned short h0 = f2bf(v0[j]), h1 = f2bf(v1[j]);
      h[j] = (short)h0; h[j + 4] = (short)h1;
      lo2[j]     = (short)f2bf(v0[j] - bf2f(h0));
      lo2[j + 4] = (short)f2bf(v1[j] - bf2f(h1));
    }
    ahi[ks] = h; alo[ks] = lo2;
  }

  const int bb = row0 >> 12, n0 = row0 & 4095;
  #pragma unroll
  for (int i = 0; i < 5; ++i) {
    const int ct = wid + i * 4;
    f32x4 acc = (f32x4){0.f, 0.f, 0.f, 0.f};
    const unsigned short* wrow = Wt + (size_t)(ct * 16 + lr) * 256 + lg * 8;
    #pragma unroll
    for (int ks = 0; ks < 8; ++ks) {
      short8 bh = *(const short8*)(wrow + ks * 32);
      acc = MFMA16(ahi[ks], bh, acc);
    }
    if (i == 0) {  // ct = wid < 4: q/k columns, split-bf16 precision
      const unsigned short* lrow = Wlo + (size_t)(ct * 16 + lr) * 256 + lg * 8;
      #pragma unroll
      for (int ks = 0; ks < 8; ++ks) {
        short8 bh = *(const short8*)(wrow + ks * 32);
        short8 bl = *(const short8*)(lrow + ks * 32);
        acc = MFMA16(alo[ks], bh, acc);
        acc = MFMA16(ahi[ks], bl, acc);
      }
    }
    const int col = ct * 16 + lr;
    const float bias = bcat[col];
    #pragma unroll
    for (int r = 0; r < 4; ++r) {
      const int row = lg * 4 + r;   // D layout: row=(l>>4)*4+r, col=l&15
      unsigned short h = f2bf(acc[r] + bias);
      if (col < 32)      Qb[(size_t)(row0 + row) * 32 + col] = h;
      else if (col < 64) Kb[(size_t)(row0 + row) * 32 + (col - 32)] = h;
      else               Vt[((size_t)bb * 256 + (col - 64)) * 4096 + n0 + row] = h;
    }
  }
}

// ---------------- flash attention v2b: 32x32 MFMA, swapped QK^T, in-reg softmax
// Block = 4 waves (kv quarters) x [32 q-rows x 128 channels]. Grid = b x qt x ch.
// S^T = mfma32(K, Q^T): lane l holds 16 kv-scores of q-row (l&31).
// Cross-half (lane^32) exchange via __shfl_xor (known-good), not permlane.
__global__ __launch_bounds__(256, 3) void attn_kernel(
    const unsigned short* __restrict__ Qb,
    const unsigned short* __restrict__ Kb,
    const unsigned short* __restrict__ Vt,
    const float* __restrict__ x,
    const float* __restrict__ gamma_p,
    float* __restrict__ out)
{
  const int tid = threadIdx.x, wid = tid >> 6;   // kv quarter
  const int l = tid & 63, lq = l & 31, lh = l >> 5;

  // XCD swizzle: batch b -> XCDs {2b,2b+1}; bijective over 1024 blocks.
  const int bid = blockIdx.x;
  const int b  = (bid & 7) >> 1;
  const int u  = ((bid >> 3) << 1) | (bid & 1);   // 0..255
  const int qt = u >> 1, ch = u & 1;
  const int n0 = qt << 5;          // 32 q-rows
  const int c0 = ch << 7;          // 128 channels

  const unsigned short* Kbase = Kb + (size_t)b * 4096 * 32;
  const unsigned short* Vbase = Vt + ((size_t)b * 256 + c0) * 4096;

  // Q^T B-fragments (d = 32 -> 2 K-steps), resident all kernel
  const unsigned short* qrow = Qb + (size_t)(b * 4096 + n0 + lq) * 32 + lh * 8;
  const short8 qf0 = *(const short8*)(qrow);
  const short8 qf1 = *(const short8*)(qrow + 16);

  f32x16 O[4];
  #pragma unroll
  for (int cc = 0; cc < 4; ++cc)
    #pragma unroll
    for (int r = 0; r < 16; ++r) O[cc][r] = 0.f;
  float m = -1e30f, lsum = 0.f;

  const int kv0 = wid << 10;
  for (int it = 0; it < 32; ++it) {
    const int kv = kv0 + (it << 5);

    // S^T = K @ Q^T  (two K-steps over d)
    const unsigned short* krow = Kbase + (size_t)(kv + lq) * 32 + lh * 8;
    short8 kf0 = *(const short8*)(krow);
    short8 kf1 = *(const short8*)(krow + 16);
    f32x16 S;
    #pragma unroll
    for (int r = 0; r < 16; ++r) S[r] = 0.f;
    S = MFMA32(kf0, qf0, S);
    S = MFMA32(kf1, qf1, S);
    // lane holds S^T[kv_row][q=lq], kv_row = (r&3) + 8*(r>>2) + 4*lh

    // row max: in-register chain + cross-half
    float mx = S[0];
    #pragma unroll
    for (int r = 1; r < 16; ++r) mx = fmaxf(mx, S[r]);
    mx = xhalf_max(mx);   // now identical for lane pair (l, l^32)

    // T13 defer-max
    if (__any((int)(mx > m + 8.f))) {
      float mn = fmaxf(m, mx);
      float sc = __expf(m - mn);
      m = mn; lsum *= sc;
      #pragma unroll
      for (int cc = 0; cc < 4; ++cc)
        #pragma unroll
        for (int r = 0; r < 16; ++r) O[cc][r] *= sc;
    }

    // P = exp(S - m) in place; row sum (m identical across the lane pair)
    float s = 0.f;
    #pragma unroll
    for (int r = 0; r < 16; ++r) { S[r] = __expf(S[r] - m); s += S[r]; }
    lsum += xhalf_add(s);

    // ---- P^T B-frags: cvt_pk words + cross-half exchange via shfl_xor ----
    // lh=0 lane owns kv rows {0-3,8-11} in S[0..7]; lh=1 owns {4-7,12-15}.
    // B-frag ks=0 needs rows lh*8..lh*8+7 :
    //   lh=0: {a0,b0, partner a0, partner b0} ; lh=1: {partner c0, partner d0, c0, d0}
    unsigned int a0 = cvtpk(S[0], S[1]),  b0w = cvtpk(S[2], S[3]);
    unsigned int c0w = cvtpk(S[4], S[5]), d0w = cvtpk(S[6], S[7]);
    unsigned int pa0 = (unsigned int)__shfl_xor((int)a0, 32);
    unsigned int pb0 = (unsigned int)__shfl_xor((int)b0w, 32);
    unsigned int pc0 = (unsigned int)__shfl_xor((int)c0w, 32);
    unsigned int pd0 = (unsigned int)__shfl_xor((int)d0w, 32);
    int4v w0;
    w0[0] = (int)(lh ? pc0 : a0);
    w0[1] = (int)(lh ? pd0 : b0w);
    w0[2] = (int)(lh ? c0w : pa0);
    w0[3] = (int)(lh ? d0w : pb0);

    unsigned int a1 = cvtpk(S[8], S[9]),   b1w = cvtpk(S[10], S[11]);
    unsigned int c1w = cvtpk(S[12], S[13]), d1w = cvtpk(S[14], S[15]);
    unsigned int pa1 = (unsigned int)__shfl_xor((int)a1, 32);
    unsigned int pb1 = (unsigned int)__shfl_xor((int)b1w, 32);
    unsigned int pc1 = (unsigned int)__shfl_xor((int)c1w, 32);
    unsigned int pd1 = (unsigned int)__shfl_xor((int)d1w, 32);
    int4v w1;
    w1[0] = (int)(lh ? pc1 : a1);
    w1[1] = (int)(lh ? pd1 : b1w);
    w1[2] = (int)(lh ? c1w : pa1);
    w1[3] = (int)(lh ? d1w : pb1);

    short8 pb_0 = *(short8*)&w0;   // B-frag, kv 0-15
    short8 pb_1 = *(short8*)&w1;   // B-frag, kv 16-31

    // O^T[c][q] += V^T @ P^T : 4 channel chunks x 2 K-steps
    #pragma unroll
    for (int cc = 0; cc < 4; ++cc) {
      const unsigned short* vrow = Vbase + (size_t)(cc * 32 + lq) * 4096 + kv + lh * 8;
      short8 vf0 = *(const short8*)(vrow);
      short8 vf1 = *(const short8*)(vrow + 16);
      O[cc] = MFMA32(vf0, pb_0, O[cc]);
      O[cc] = MFMA32(vf1, pb_1, O[cc]);
    }
  }

  // ---- cross-wave (4 kv quarters) online-softmax merge ----
  __shared__ float msh[4][32];
  __shared__ float lsh[4][32];
  __shared__ float Osh[32][133];   // [q][c], padded

  if (lh == 0) msh[wid][lq] = m;
  __syncthreads();
  const float M = fmaxf(fmaxf(msh[0][lq], msh[1][lq]),
                        fmaxf(msh[2][lq], msh[3][lq]));
  const float sw = __expf(m - M);
  lsum *= sw;
  if (lh == 0) lsh[wid][lq] = lsum;
  #pragma unroll
  for (int w = 0; w < 4; ++w) {
    __syncthreads();
    if (wid == w) {
      #pragma unroll
      for (int cc = 0; cc < 4; ++cc)
        #pragma unroll
        for (int r = 0; r < 16; ++r) {
          const int c = cc * 32 + (r & 3) + ((r >> 2) << 3) + (lh << 2);
          float v = sw * O[cc][r];
          float* p = &Osh[lq][c];
          if (w == 0) *p = v; else *p += v;
        }
    }
  }
  __syncthreads();

  // ---- epilogue: out = gamma*(Osh/L) + x over 32q x 128c, float4 stores ----
  const float g = gamma_p[0];
  #pragma unroll
  for (int i = 0; i < 4; ++i) {
    const int p = tid + (i << 8);          // 1024 quads
    const int q = p >> 5, c = (p & 31) << 2;
    const float L = lsh[0][q] + lsh[1][q] + lsh[2][q] + lsh[3][q];
    const float s = g / L;
    const size_t idx = (size_t)(b * 4096 + n0 + q) * 256 + c0 + c;
    f32x4 xi = *(const f32x4*)(x + idx);
    f32x4 res;
    #pragma unroll
    for (int j = 0; j < 4; ++j) res[j] = Osh[q][c + j] * s + xi[j];
    *(f32x4*)(out + idx) = res;
  }
}

extern "C" void kernel_launch(void* const* d_in, const int* in_sizes, int n_in,
                              void* d_out, int out_size, void* d_ws, size_t ws_size,
                              hipStream_t stream)
{
  const float* x     = (const float*)d_in[0];
  const float* Wq    = (const float*)d_in[1];
  const float* bq    = (const float*)d_in[2];
  const float* Wk    = (const float*)d_in[3];
  const float* bk    = (const float*)d_in[4];
  const float* Wv    = (const float*)d_in[5];
  const float* bv    = (const float*)d_in[6];
  const float* gamma = (const float*)d_in[7];
  float* out = (float*)d_out;

  char* ws = (char*)d_ws;
  unsigned short* Qb  = (unsigned short*)(ws);
  unsigned short* Kb  = (unsigned short*)(ws + (1u << 20));
  unsigned short* Vt  = (unsigned short*)(ws + (2u << 20));
  unsigned short* Wt  = (unsigned short*)(ws + (10u << 20));
  unsigned short* Wlo = (unsigned short*)(ws + (10u << 20) + (256u << 10));
  float*          bcat = (float*)(ws + (10u << 20) + (320u << 10));

  pack_w_kernel<<<dim3(320), dim3(64), 0, stream>>>(Wq, bq, Wk, bk, Wv, bv, Wt, Wlo, bcat);
  qkv_kernel<<<dim3(1024), dim3(256), 0, stream>>>(x, Wt, Wlo, bcat, Qb, Kb, Vt);
  attn_kernel<<<dim3(1024), dim3(256), 0, stream>>>(Qb, Kb, Vt, x, gamma, out);
}

// Round 10
// 177.479 us; speedup vs baseline: 2.2785x; 1.4675x over previous
//
#include <hip/hip_runtime.h>

// AttentionBlock: x[4,64,64,256] f32; q=x@Wq+bq (d=32), k=x@Wk+bk, v=x@Wv+bv (256)
// scores=q@k^T (no 1/sqrt(d)), softmax, out = gamma*(attn@v) + x.
//
// v3b: FRAGMENT-LINEAR layouts for K, V, W so every MFMA operand load in the
// hot loops is `base + laneId*16` (coalesced 1KB/instr) instead of a 64-lane
// scatter at 0.5-8KB stride (round-8 counters: attn latency-bound on V-frag
// scatter, ~11K cyc/iter). v3b fixes two global-vs-local block indices in the
// K/V producers (desk-audit, round 9).
//
// ws layout:
//   Qb  bf16 [4][4096][32]            @ 0      (1 MiB)  row-major (read once)
//   Kf  bf16 [4][128][128][8]         @ 1 MiB  (1 MiB)  ((b*128+kvb)*128 + lq + 32*(d/8))*8 + d%8
//   Vf  bf16 [4][8][256][64][8]       @ 2 MiB  (8 MiB)  (((b*8+c/32)*256 + n/16)*64 + (c&31) + 32*((n>>3)&1))*8 + n%8
//   Wf  bf16 [20][8][64][8]           @ 10 MiB (160 KiB) ((ct*8+ks)*64 + lane)*8 + j
//   Wlo bf16 [4][8][64][8]            @ +256K  (32 KiB)
//   bcat f32 [320]                    @ +320K

using short8 = __attribute__((ext_vector_type(8))) short;
using f32x4  = __attribute__((ext_vector_type(4))) float;
using f32x16 = __attribute__((ext_vector_type(16))) float;
using int4v  = __attribute__((ext_vector_type(4))) int;
using us4    = __attribute__((ext_vector_type(4))) unsigned short;

#define MFMA16(a,b,c) __builtin_amdgcn_mfma_f32_16x16x32_bf16((a),(b),(c),0,0,0)
#define MFMA32(a,b,c) __builtin_amdgcn_mfma_f32_32x32x16_bf16((a),(b),(c),0,0,0)

__device__ __forceinline__ unsigned short f2bf(float f) {
  union { float f; unsigned int u; } a; a.f = f;
  unsigned int u = a.u;
  return (unsigned short)((u + 0x7fffu + ((u >> 16) & 1u)) >> 16);  // RNE
}
__device__ __forceinline__ float bf2f(unsigned short h) {
  union { unsigned int u; float f; } a; a.u = ((unsigned int)h) << 16;
  return a.f;
}
__device__ __forceinline__ unsigned int cvtpk(float lo, float hi) {
  unsigned int r;
  asm("v_cvt_pk_bf16_f32 %0, %1, %2" : "=v"(r) : "v"(lo), "v"(hi));
  return r;
}
__device__ __forceinline__ float xhalf_max(float v) {
  return fmaxf(v, __shfl_xor(v, 32));
}
__device__ __forceinline__ float xhalf_add(float v) {
  return v + __shfl_xor(v, 32);
}

// ---------------- pack W into fragment-linear bf16 (+ lo residual q/k) ------
__global__ __launch_bounds__(64) void pack_w_kernel(
    const float* __restrict__ Wq, const float* __restrict__ bq,
    const float* __restrict__ Wk, const float* __restrict__ bk,
    const float* __restrict__ Wv, const float* __restrict__ bv,
    unsigned short* __restrict__ Wf, unsigned short* __restrict__ Wlo,
    float* __restrict__ bcat)
{
  const int c = blockIdx.x;   // 0..319 packed output column
  const int t = threadIdx.x;  // 0..63
  const float* W; int cc, stride;
  if (c < 32)      { W = Wq; cc = c;      stride = 32;  }
  else if (c < 64) { W = Wk; cc = c - 32; stride = 32;  }
  else             { W = Wv; cc = c - 64; stride = 256; }
  const int ct = c >> 4, lr = c & 15;
  for (int k = t; k < 256; k += 64) {
    float w = W[(size_t)k * stride + cc];
    unsigned short hi = f2bf(w);
    const int ks = k >> 5, lg = (k >> 3) & 3, j = k & 7;
    const int idx = (((ct * 8 + ks) * 64) + lr + 16 * lg) * 8 + j;
    Wf[idx] = hi;
    if (c < 64) Wlo[idx] = f2bf(w - bf2f(hi));
  }
  if (t == 0)
    bcat[c] = (c < 32) ? bq[c] : (c < 64) ? bk[c - 32] : bv[c - 64];
}

// ---------------- fused QKV projection GEMM [16384,256]@[256,320] -----------
// 4 waves/block, 16 rows/block; wave w owns ct tiles {w, w+4, w+8, w+12, w+16}.
// W B-frags are fragment-linear (coalesced lane*16 loads). K/V outputs are
// stored in the attention kernel's fragment order.
__global__ __launch_bounds__(256, 4) void qkv_kernel(
    const float* __restrict__ x,
    const unsigned short* __restrict__ Wf,
    const unsigned short* __restrict__ Wlo,
    const float* __restrict__ bcat,
    unsigned short* __restrict__ Qb, unsigned short* __restrict__ Kf,
    unsigned short* __restrict__ Vf)
{
  const int tid = threadIdx.x, wid = tid >> 6;
  const int l = tid & 63, lr = l & 15, lg = l >> 4;
  const int row0 = blockIdx.x * 16;   // global row in [0, 16384)

  // A fragments: lane holds x[row0+lr][ks*32 + lg*8 + j], hi/lo bf16 split.
  short8 ahi[8], alo[8];
  const float* xr = x + (size_t)(row0 + lr) * 256 + lg * 8;
  #pragma unroll
  for (int ks = 0; ks < 8; ++ks) {
    f32x4 v0 = *(const f32x4*)(xr + ks * 32);
    f32x4 v1 = *(const f32x4*)(xr + ks * 32 + 4);
    short8 h, lo2;
    #pragma unroll
    for (int j = 0; j < 4; ++j) {
      unsigned short h0 = f2bf(v0[j]), h1 = f2bf(v1[j]);
      h[j] = (short)h0; h[j + 4] = (short)h1;
      lo2[j]     = (short)f2bf(v0[j] - bf2f(h0));
      lo2[j + 4] = (short)f2bf(v1[j] - bf2f(h1));
    }
    ahi[ks] = h; alo[ks] = lo2;
  }

  const int bb = row0 >> 12;
  const int n0loc = row0 & 4095;   // row within batch
  #pragma unroll
  for (int i = 0; i < 5; ++i) {
    const int ct = wid + i * 4;
    f32x4 acc = (f32x4){0.f, 0.f, 0.f, 0.f};
    const unsigned short* wbase = Wf + (size_t)(ct * 8) * 512 + l * 8;
    #pragma unroll
    for (int ks = 0; ks < 8; ++ks) {
      short8 bh = *(const short8*)(wbase + ks * 512);
      acc = MFMA16(ahi[ks], bh, acc);
    }
    if (i == 0) {  // ct = wid < 4: q/k columns, split-bf16 precision
      const unsigned short* lbase = Wlo + (size_t)(ct * 8) * 512 + l * 8;
      #pragma unroll
      for (int ks = 0; ks < 8; ++ks) {
        short8 bh = *(const short8*)(wbase + ks * 512);
        short8 bl = *(const short8*)(lbase + ks * 512);
        acc = MFMA16(alo[ks], bh, acc);
        acc = MFMA16(ahi[ks], bl, acc);
      }
    }
    const int col = ct * 16 + lr;
    const float bias = bcat[col];
    unsigned short h[4];
    #pragma unroll
    for (int r = 0; r < 4; ++r) h[r] = f2bf(acc[r] + bias);

    if (col < 32) {            // Q: row-major (read once in attn, scatter ok)
      #pragma unroll
      for (int r = 0; r < 4; ++r) {
        const int row = lg * 4 + r;
        Qb[(size_t)(row0 + row) * 32 + col] = h[r];
      }
    } else if (col < 64) {     // K: fragment-linear (LOCAL kv-block index)
      const int d = col - 32, dh = d >> 3, j = d & 7;
      const int kvb = n0loc >> 5, lq0 = (n0loc & 16);
      #pragma unroll
      for (int r = 0; r < 4; ++r) {
        const int lq = lq0 + lg * 4 + r;
        Kf[(size_t)(((bb * 128 + kvb) * 128) + lq + 32 * dh) * 8 + j] = h[r];
      }
    } else {                   // V: fragment-linear, 4 bf16 packed per store
      const int cv = col - 64, ctv = cv >> 5, lc = cv & 31;
      const int kb = n0loc >> 4, kh = lg >> 1, j0 = 4 * (lg & 1);
      us4 pk = (us4){h[0], h[1], h[2], h[3]};
      *(us4*)(Vf + (size_t)((((bb * 8 + ctv) * 256 + kb) * 64) + lc + 32 * kh) * 8 + j0) = pk;
    }
  }
}

// ---------------- flash attention v3: 32x32 MFMA, fragment-linear K/V -------
// Block = 4 waves (kv quarters) x [32 q-rows x 128 channels]. Grid = b x qt x ch.
// S^T = mfma32(K, Q^T): lane l holds 16 kv-scores of q-row (l&31).
// All K/V fragment loads are base + laneId*16 (coalesced).
__global__ __launch_bounds__(256, 3) void attn_kernel(
    const unsigned short* __restrict__ Qb,
    const unsigned short* __restrict__ Kf,
    const unsigned short* __restrict__ Vf,
    const float* __restrict__ x,
    const float* __restrict__ gamma_p,
    float* __restrict__ out)
{
  const int tid = threadIdx.x, wid = tid >> 6;   // kv quarter
  const int l = tid & 63, lq = l & 31, lh = l >> 5;

  // XCD swizzle: batch b -> XCDs {2b,2b+1}; bijective over 1024 blocks.
  const int bid = blockIdx.x;
  const int b  = (bid & 7) >> 1;
  const int u  = ((bid >> 3) << 1) | (bid & 1);   // 0..255
  const int qt = u >> 1, ch = u & 1;
  const int n0 = qt << 5;          // 32 q-rows
  const int c0 = ch << 7;          // 128 channels

  // Q^T B-fragments (d = 32 -> 2 K-steps), resident all kernel
  const unsigned short* qrow = Qb + (size_t)(b * 4096 + n0 + lq) * 32 + lh * 8;
  const short8 qf0 = *(const short8*)(qrow);
  const short8 qf1 = *(const short8*)(qrow + 16);

  f32x16 O[4];
  #pragma unroll
  for (int cc = 0; cc < 4; ++cc)
    #pragma unroll
    for (int r = 0; r < 16; ++r) O[cc][r] = 0.f;
  float m = -1e30f, lsum = 0.f;

  const int kv0 = wid << 10;
  for (int it = 0; it < 32; ++it) {
    const int kv = kv0 + (it << 5);

    // S^T = K @ Q^T (two K-steps over d); Kf loads: base + l*16, +1KB
    const unsigned short* kp = Kf + (size_t)((b * 128 + (kv >> 5)) * 128) * 8 + l * 8;
    short8 kf0 = *(const short8*)(kp);
    short8 kf1 = *(const short8*)(kp + 512);
    f32x16 S;
    #pragma unroll
    for (int r = 0; r < 16; ++r) S[r] = 0.f;
    S = MFMA32(kf0, qf0, S);
    S = MFMA32(kf1, qf1, S);
    // lane holds S^T[kv_row][q=lq], kv_row = (r&3) + 8*(r>>2) + 4*lh

    // row max: in-register chain + cross-half
    float mx = S[0];
    #pragma unroll
    for (int r = 1; r < 16; ++r) mx = fmaxf(mx, S[r]);
    mx = xhalf_max(mx);

    // T13 defer-max
    if (__any((int)(mx > m + 8.f))) {
      float mn = fmaxf(m, mx);
      float sc = __expf(m - mn);
      m = mn; lsum *= sc;
      #pragma unroll
      for (int cc = 0; cc < 4; ++cc)
        #pragma unroll
        for (int r = 0; r < 16; ++r) O[cc][r] *= sc;
    }

    // P = exp(S - m) in place; row sum
    float s = 0.f;
    #pragma unroll
    for (int r = 0; r < 16; ++r) { S[r] = __expf(S[r] - m); s += S[r]; }
    lsum += xhalf_add(s);

    // ---- P^T B-frags: cvt_pk words + cross-half exchange via shfl_xor ----
    unsigned int a0 = cvtpk(S[0], S[1]),  b0w = cvtpk(S[2], S[3]);
    unsigned int c0w = cvtpk(S[4], S[5]), d0w = cvtpk(S[6], S[7]);
    unsigned int pa0 = (unsigned int)__shfl_xor((int)a0, 32);
    unsigned int pb0 = (unsigned int)__shfl_xor((int)b0w, 32);
    unsigned int pc0 = (unsigned int)__shfl_xor((int)c0w, 32);
    unsigned int pd0 = (unsigned int)__shfl_xor((int)d0w, 32);
    int4v w0;
    w0[0] = (int)(lh ? pc0 : a0);
    w0[1] = (int)(lh ? pd0 : b0w);
    w0[2] = (int)(lh ? c0w : pa0);
    w0[3] = (int)(lh ? d0w : pb0);

    unsigned int a1 = cvtpk(S[8], S[9]),   b1w = cvtpk(S[10], S[11]);
    unsigned int c1w = cvtpk(S[12], S[13]), d1w = cvtpk(S[14], S[15]);
    unsigned int pa1 = (unsigned int)__shfl_xor((int)a1, 32);
    unsigned int pb1 = (unsigned int)__shfl_xor((int)b1w, 32);
    unsigned int pc1 = (unsigned int)__shfl_xor((int)c1w, 32);
    unsigned int pd1 = (unsigned int)__shfl_xor((int)d1w, 32);
    int4v w1;
    w1[0] = (int)(lh ? pc1 : a1);
    w1[1] = (int)(lh ? pd1 : b1w);
    w1[2] = (int)(lh ? c1w : pa1);
    w1[3] = (int)(lh ? d1w : pb1);

    short8 pb_0 = *(short8*)&w0;   // B-frag, kv 0-15
    short8 pb_1 = *(short8*)&w1;   // B-frag, kv 16-31

    // O^T[c][q] += V^T @ P^T : Vf loads are base + l*16 (coalesced)
    const int kb = kv >> 4;
    #pragma unroll
    for (int cc = 0; cc < 4; ++cc) {
      const unsigned short* vp =
          Vf + (size_t)(((b * 8 + ch * 4 + cc) * 256 + kb) * 64) * 8 + l * 8;
      short8 vf0 = *(const short8*)(vp);
      short8 vf1 = *(const short8*)(vp + 512);
      O[cc] = MFMA32(vf0, pb_0, O[cc]);
      O[cc] = MFMA32(vf1, pb_1, O[cc]);
    }
  }

  // ---- cross-wave (4 kv quarters) online-softmax merge ----
  __shared__ float msh[4][32];
  __shared__ float lsh[4][32];
  __shared__ float Osh[32][133];   // [q][c], padded

  if (lh == 0) msh[wid][lq] = m;
  __syncthreads();
  const float M = fmaxf(fmaxf(msh[0][lq], msh[1][lq]),
                        fmaxf(msh[2][lq], msh[3][lq]));
  const float sw = __expf(m - M);
  lsum *= sw;
  if (lh == 0) lsh[wid][lq] = lsum;
  #pragma unroll
  for (int w = 0; w < 4; ++w) {
    __syncthreads();
    if (wid == w) {
      #pragma unroll
      for (int cc = 0; cc < 4; ++cc)
        #pragma unroll
        for (int r = 0; r < 16; ++r) {
          const int c = cc * 32 + (r & 3) + ((r >> 2) << 3) + (lh << 2);
          float v = sw * O[cc][r];
          float* p = &Osh[lq][c];
          if (w == 0) *p = v; else *p += v;
        }
    }
  }
  __syncthreads();

  // ---- epilogue: out = gamma*(Osh/L) + x over 32q x 128c, float4 stores ----
  const float g = gamma_p[0];
  #pragma unroll
  for (int i = 0; i < 4; ++i) {
    const int p = tid + (i << 8);          // 1024 quads
    const int q = p >> 5, c = (p & 31) << 2;
    const float L = lsh[0][q] + lsh[1][q] + lsh[2][q] + lsh[3][q];
    const float s = g / L;
    const size_t idx = (size_t)(b * 4096 + n0 + q) * 256 + c0 + c;
    f32x4 xi = *(const f32x4*)(x + idx);
    f32x4 res;
    #pragma unroll
    for (int j = 0; j < 4; ++j) res[j] = Osh[q][c + j] * s + xi[j];
    *(f32x4*)(out + idx) = res;
  }
}

extern "C" void kernel_launch(void* const* d_in, const int* in_sizes, int n_in,
                              void* d_out, int out_size, void* d_ws, size_t ws_size,
                              hipStream_t stream)
{
  const float* x     = (const float*)d_in[0];
  const float* Wq    = (const float*)d_in[1];
  const float* bq    = (const float*)d_in[2];
  const float* Wk    = (const float*)d_in[3];
  const float* bk    = (const float*)d_in[4];
  const float* Wv    = (const float*)d_in[5];
  const float* bv    = (const float*)d_in[6];
  const float* gamma = (const float*)d_in[7];
  float* out = (float*)d_out;

  char* ws = (char*)d_ws;
  unsigned short* Qb  = (unsigned short*)(ws);
  unsigned short* Kf  = (unsigned short*)(ws + (1u << 20));
  unsigned short* Vf  = (unsigned short*)(ws + (2u << 20));
  unsigned short* Wf  = (unsigned short*)(ws + (10u << 20));
  unsigned short* Wlo = (unsigned short*)(ws + (10u << 20) + (256u << 10));
  float*          bcat = (float*)(ws + (10u << 20) + (320u << 10));

  pack_w_kernel<<<dim3(320), dim3(64), 0, stream>>>(Wq, bq, Wk, bk, Wv, bv, Wf, Wlo, bcat);
  qkv_kernel<<<dim3(1024), dim3(256), 0, stream>>>(x, Wf, Wlo, bcat, Qb, Kf, Vf);
  attn_kernel<<<dim3(1024), dim3(256), 0, stream>>>(Qb, Kf, Vf, x, gamma, out);
}

// Round 16
// 166.002 us; speedup vs baseline: 2.4360x; 1.0691x over previous
//
#include <hip/hip_runtime.h>

// AttentionBlock: x[4,64,64,256] f32; q=x@Wq+bq (d=32), k=x@Wk+bk, v=x@Wv+bv (256)
// scores=q@k^T (no 1/sqrt(d)), softmax, out = gamma*(attn@v) + x.
//
// v4: v3b + (a) V rows stored pre-permuted by sigma = swap-bits-2,3 of the
// in-block kv index, so the PV B-fragment is a DIRECT cvt_pk of the S regs
// (zero cross-lane exchange; was 8 ds_bpermute + 8 selects per iter on the
// critical path); (b) qkv restructured ks-outer to cut register pressure
// (A-frag transient per ks instead of 64 VGPR held) -> no spills at the
// launch_bounds(256,4) 128-VGPR cap.
//
// ws layout:
//   Qb  bf16 [4][4096][32]            @ 0      (1 MiB)  row-major (read once)
//   Kf  bf16 [4][128][128][8]         @ 1 MiB  (1 MiB)
//   Vf  bf16 [4][8][256][64][8]       @ 2 MiB  (8 MiB)  sigma-permuted rows
//   Wf  bf16 [20][8][64][8]           @ 10 MiB (160 KiB)
//   Wlo bf16 [4][8][64][8]            @ +256K  (32 KiB)
//   bcat f32 [320]                    @ +320K

using short8 = __attribute__((ext_vector_type(8))) short;
using f32x4  = __attribute__((ext_vector_type(4))) float;
using f32x16 = __attribute__((ext_vector_type(16))) float;
using int4v  = __attribute__((ext_vector_type(4))) int;
using us4    = __attribute__((ext_vector_type(4))) unsigned short;

#define MFMA16(a,b,c) __builtin_amdgcn_mfma_f32_16x16x32_bf16((a),(b),(c),0,0,0)
#define MFMA32(a,b,c) __builtin_amdgcn_mfma_f32_32x32x16_bf16((a),(b),(c),0,0,0)

__device__ __forceinline__ unsigned short f2bf(float f) {
  union { float f; unsigned int u; } a; a.f = f;
  unsigned int u = a.u;
  return (unsigned short)((u + 0x7fffu + ((u >> 16) & 1u)) >> 16);  // RNE
}
__device__ __forceinline__ float bf2f(unsigned short h) {
  union { unsigned int u; float f; } a; a.u = ((unsigned int)h) << 16;
  return a.f;
}
__device__ __forceinline__ unsigned int cvtpk(float lo, float hi) {
  unsigned int r;
  asm("v_cvt_pk_bf16_f32 %0, %1, %2" : "=v"(r) : "v"(lo), "v"(hi));
  return r;
}
__device__ __forceinline__ float xhalf_max(float v) {
  return fmaxf(v, __shfl_xor(v, 32));
}
__device__ __forceinline__ float xhalf_add(float v) {
  return v + __shfl_xor(v, 32);
}

// ---------------- pack W into fragment-linear bf16 (+ lo residual q/k) ------
__global__ __launch_bounds__(64) void pack_w_kernel(
    const float* __restrict__ Wq, const float* __restrict__ bq,
    const float* __restrict__ Wk, const float* __restrict__ bk,
    const float* __restrict__ Wv, const float* __restrict__ bv,
    unsigned short* __restrict__ Wf, unsigned short* __restrict__ Wlo,
    float* __restrict__ bcat)
{
  const int c = blockIdx.x;   // 0..319 packed output column
  const int t = threadIdx.x;  // 0..63
  const float* W; int cc, stride;
  if (c < 32)      { W = Wq; cc = c;      stride = 32;  }
  else if (c < 64) { W = Wk; cc = c - 32; stride = 32;  }
  else             { W = Wv; cc = c - 64; stride = 256; }
  const int ct = c >> 4, lr = c & 15;
  for (int k = t; k < 256; k += 64) {
    float w = W[(size_t)k * stride + cc];
    unsigned short hi = f2bf(w);
    const int ks = k >> 5, lg = (k >> 3) & 3, j = k & 7;
    const int idx = (((ct * 8 + ks) * 64) + lr + 16 * lg) * 8 + j;
    Wf[idx] = hi;
    if (c < 64) Wlo[idx] = f2bf(w - bf2f(hi));
  }
  if (t == 0)
    bcat[c] = (c < 32) ? bq[c] : (c < 64) ? bk[c - 32] : bv[c - 64];
}

// ---------------- fused QKV projection GEMM [16384,256]@[256,320] -----------
// ks-OUTER: A-frag built per K-step (transient 16 VGPR), acc[5] held (20).
// Peak ~70 VGPR -> no spills at the (256,4) 128-cap. Same loads/MFMAs as v3b.
__global__ __launch_bounds__(256, 4) void qkv_kernel(
    const float* __restrict__ x,
    const unsigned short* __restrict__ Wf,
    const unsigned short* __restrict__ Wlo,
    const float* __restrict__ bcat,
    unsigned short* __restrict__ Qb, unsigned short* __restrict__ Kf,
    unsigned short* __restrict__ Vf)
{
  const int tid = threadIdx.x, wid = tid >> 6;
  const int l = tid & 63, lr = l & 15, lg = l >> 4;
  const int row0 = blockIdx.x * 16;   // global row in [0, 16384)
  const int bb = row0 >> 12;
  const int n0loc = row0 & 4095;      // row within batch

  f32x4 acc[5];
  #pragma unroll
  for (int i = 0; i < 5; ++i) acc[i] = (f32x4){0.f, 0.f, 0.f, 0.f};

  const float* xr = x + (size_t)(row0 + lr) * 256 + lg * 8;
  #pragma unroll
  for (int ks = 0; ks < 8; ++ks) {
    // A fragment for this K-step: x[row0+lr][ks*32 + lg*8 + j], hi/lo split
    f32x4 v0 = *(const f32x4*)(xr + ks * 32);
    f32x4 v1 = *(const f32x4*)(xr + ks * 32 + 4);
    short8 h, lo2;
    #pragma unroll
    for (int j = 0; j < 4; ++j) {
      unsigned short h0 = f2bf(v0[j]), h1 = f2bf(v1[j]);
      h[j] = (short)h0; h[j + 4] = (short)h1;
      lo2[j]     = (short)f2bf(v0[j] - bf2f(h0));
      lo2[j + 4] = (short)f2bf(v1[j] - bf2f(h1));
    }
    #pragma unroll
    for (int i = 0; i < 5; ++i) {
      const int ct = wid + i * 4;
      short8 bh = *(const short8*)(Wf + (size_t)((ct * 8 + ks) * 64 + l) * 8);
      acc[i] = MFMA16(h, bh, acc[i]);
      if (i == 0) {  // ct = wid < 4: q/k columns, split-bf16 precision
        short8 bl = *(const short8*)(Wlo + (size_t)((wid * 8 + ks) * 64 + l) * 8);
        acc[0] = MFMA16(lo2, bh, acc[0]);
        acc[0] = MFMA16(h, bl, acc[0]);
      }
    }
  }

  #pragma unroll
  for (int i = 0; i < 5; ++i) {
    const int ct = wid + i * 4;
    const int col = ct * 16 + lr;
    const float bias = bcat[col];
    unsigned short h[4];
    #pragma unroll
    for (int r = 0; r < 4; ++r) h[r] = f2bf(acc[i][r] + bias);

    if (col < 32) {            // Q: row-major (read once in attn)
      #pragma unroll
      for (int r = 0; r < 4; ++r)
        Qb[(size_t)(row0 + lg * 4 + r) * 32 + col] = h[r];
    } else if (col < 64) {     // K: fragment-linear (local kv-block index)
      const int d = col - 32, dh = d >> 3, j = d & 7;
      const int kvb = n0loc >> 5, lq0 = (n0loc & 16);
      #pragma unroll
      for (int r = 0; r < 4; ++r) {
        const int lq = lq0 + lg * 4 + r;
        Kf[(size_t)(((bb * 128 + kvb) * 128) + lq + 32 * dh) * 8 + j] = h[r];
      }
    } else {                   // V: fragment-linear, sigma-PERMUTED slot:
      // local row n = lg*4+r -> slot = swap bits2,3(n):
      //   kh = lg&1, j0 = 4*(lg>>1), element j0+r
      const int cv = col - 64, ctv = cv >> 5, lc = cv & 31;
      const int kb = n0loc >> 4, kh = lg & 1, j0 = 4 * (lg >> 1);
      us4 pk = (us4){h[0], h[1], h[2], h[3]};
      *(us4*)(Vf + (size_t)((((bb * 8 + ctv) * 256 + kb) * 64) + lc + 32 * kh) * 8 + j0) = pk;
    }
  }
}

// ---------------- flash attention v4: zero-exchange PV ----------------------
// Block = 4 waves (kv quarters) x [32 q-rows x 128 channels]. Grid = b x qt x ch.
// S^T = mfma32(K, Q^T); V stored sigma-permuted -> PV B-frag = direct cvt_pk
// of S regs (no cross-lane ops between softmax and PV).
__global__ __launch_bounds__(256, 3) void attn_kernel(
    const unsigned short* __restrict__ Qb,
    const unsigned short* __restrict__ Kf,
    const unsigned short* __restrict__ Vf,
    const float* __restrict__ x,
    const float* __restrict__ gamma_p,
    float* __restrict__ out)
{
  const int tid = threadIdx.x, wid = tid >> 6;   // kv quarter
  const int l = tid & 63, lq = l & 31, lh = l >> 5;

  // XCD swizzle: batch b -> XCDs {2b,2b+1}; bijective over 1024 blocks.
  const int bid = blockIdx.x;
  const int b  = (bid & 7) >> 1;
  const int u  = ((bid >> 3) << 1) | (bid & 1);   // 0..255
  const int qt = u >> 1, ch = u & 1;
  const int n0 = qt << 5;          // 32 q-rows
  const int c0 = ch << 7;          // 128 channels

  // Q^T B-fragments (d = 32 -> 2 K-steps), resident all kernel
  const unsigned short* qrow = Qb + (size_t)(b * 4096 + n0 + lq) * 32 + lh * 8;
  const short8 qf0 = *(const short8*)(qrow);
  const short8 qf1 = *(const short8*)(qrow + 16);

  f32x16 O[4];
  #pragma unroll
  for (int cc = 0; cc < 4; ++cc)
    #pragma unroll
    for (int r = 0; r < 16; ++r) O[cc][r] = 0.f;
  float m = -1e30f, lsum = 0.f;

  const int kv0 = wid << 10;
  for (int it = 0; it < 32; ++it) {
    const int kv = kv0 + (it << 5);

    // S^T = K @ Q^T (two K-steps over d); Kf loads: base + l*16, +1KB
    const unsigned short* kp = Kf + (size_t)((b * 128 + (kv >> 5)) * 128) * 8 + l * 8;
    short8 kf0 = *(const short8*)(kp);
    short8 kf1 = *(const short8*)(kp + 512);
    f32x16 S;
    #pragma unroll
    for (int r = 0; r < 16; ++r) S[r] = 0.f;
    S = MFMA32(kf0, qf0, S);
    S = MFMA32(kf1, qf1, S);
    // lane holds S^T[kv_row][q=lq], kv_row = (r&3) + 8*(r>>2) + 4*lh

    // row max: balanced tree + cross-half
    float t0 = fmaxf(fmaxf(S[0], S[1]),  fmaxf(S[2], S[3]));
    float t1 = fmaxf(fmaxf(S[4], S[5]),  fmaxf(S[6], S[7]));
    float t2 = fmaxf(fmaxf(S[8], S[9]),  fmaxf(S[10], S[11]));
    float t3 = fmaxf(fmaxf(S[12], S[13]), fmaxf(S[14], S[15]));
    float mx = xhalf_max(fmaxf(fmaxf(t0, t1), fmaxf(t2, t3)));

    // T13 defer-max
    if (__any((int)(mx > m + 8.f))) {
      float mn = fmaxf(m, mx);
      float sc = __expf(m - mn);
      m = mn; lsum *= sc;
      #pragma unroll
      for (int cc = 0; cc < 4; ++cc)
        #pragma unroll
        for (int r = 0; r < 16; ++r) O[cc][r] *= sc;
    }

    // P = exp(S - m) in place; row sum
    float s = 0.f;
    #pragma unroll
    for (int r = 0; r < 16; ++r) { S[r] = __expf(S[r] - m); s += S[r]; }
    lsum += xhalf_add(s);

    // ---- P^T B-frags: DIRECT cvt_pk (V rows sigma-permuted in Vf) ----
    int4v w0, w1;
    w0[0] = (int)cvtpk(S[0], S[1]);   w0[1] = (int)cvtpk(S[2], S[3]);
    w0[2] = (int)cvtpk(S[4], S[5]);   w0[3] = (int)cvtpk(S[6], S[7]);
    w1[0] = (int)cvtpk(S[8], S[9]);   w1[1] = (int)cvtpk(S[10], S[11]);
    w1[2] = (int)cvtpk(S[12], S[13]); w1[3] = (int)cvtpk(S[14], S[15]);
    short8 pb_0 = *(short8*)&w0;   // B-frag, kv-block 0 (sigma order)
    short8 pb_1 = *(short8*)&w1;   // B-frag, kv-block 1

    // O^T[c][q] += V^T @ P^T : Vf loads are base + l*16 (coalesced)
    const int kb = kv >> 4;
    #pragma unroll
    for (int cc = 0; cc < 4; ++cc) {
      const unsigned short* vp =
          Vf + (size_t)(((b * 8 + ch * 4 + cc) * 256 + kb) * 64) * 8 + l * 8;
      short8 vf0 = *(const short8*)(vp);
      short8 vf1 = *(const short8*)(vp + 512);
      O[cc] = MFMA32(vf0, pb_0, O[cc]);
      O[cc] = MFMA32(vf1, pb_1, O[cc]);
    }
  }

  // ---- cross-wave (4 kv quarters) online-softmax merge ----
  __shared__ float msh[4][32];
  __shared__ float lsh[4][32];
  __shared__ float Osh[32][133];   // [q][c], padded

  if (lh == 0) msh[wid][lq] = m;
  __syncthreads();
  const float M = fmaxf(fmaxf(msh[0][lq], msh[1][lq]),
                        fmaxf(msh[2][lq], msh[3][lq]));
  const float sw = __expf(m - M);
  lsum *= sw;
  if (lh == 0) lsh[wid][lq] = lsum;
  #pragma unroll
  for (int w = 0; w < 4; ++w) {
    __syncthreads();
    if (wid == w) {
      #pragma unroll
      for (int cc = 0; cc < 4; ++cc)
        #pragma unroll
        for (int r = 0; r < 16; ++r) {
          const int c = cc * 32 + (r & 3) + ((r >> 2) << 3) + (lh << 2);
          float v = sw * O[cc][r];
          float* p = &Osh[lq][c];
          if (w == 0) *p = v; else *p += v;
        }
    }
  }
  __syncthreads();

  // ---- epilogue: out = gamma*(Osh/L) + x over 32q x 128c, float4 stores ----
  const float g = gamma_p[0];
  #pragma unroll
  for (int i = 0; i < 4; ++i) {
    const int p = tid + (i << 8);          // 1024 quads
    const int q = p >> 5, c = (p & 31) << 2;
    const float L = lsh[0][q] + lsh[1][q] + lsh[2][q] + lsh[3][q];
    const float s = g / L;
    const size_t idx = (size_t)(b * 4096 + n0 + q) * 256 + c0 + c;
    f32x4 xi = *(const f32x4*)(x + idx);
    f32x4 res;
    #pragma unroll
    for (int j = 0; j < 4; ++j) res[j] = Osh[q][c + j] * s + xi[j];
    *(f32x4*)(out + idx) = res;
  }
}

extern "C" void kernel_launch(void* const* d_in, const int* in_sizes, int n_in,
                              void* d_out, int out_size, void* d_ws, size_t ws_size,
                              hipStream_t stream)
{
  const float* x     = (const float*)d_in[0];
  const float* Wq    = (const float*)d_in[1];
  const float* bq    = (const float*)d_in[2];
  const float* Wk    = (const float*)d_in[3];
  const float* bk    = (const float*)d_in[4];
  const float* Wv    = (const float*)d_in[5];
  const float* bv    = (const float*)d_in[6];
  const float* gamma = (const float*)d_in[7];
  float* out = (float*)d_out;

  char* ws = (char*)d_ws;
  unsigned short* Qb  = (unsigned short*)(ws);
  unsigned short* Kf  = (unsigned short*)(ws + (1u << 20));
  unsigned short* Vf  = (unsigned short*)(ws + (2u << 20));
  unsigned short* Wf  = (unsigned short*)(ws + (10u << 20));
  unsigned short* Wlo = (unsigned short*)(ws + (10u << 20) + (256u << 10));
  float*          bcat = (float*)(ws + (10u << 20) + (320u << 10));

  pack_w_kernel<<<dim3(320), dim3(64), 0, stream>>>(Wq, bq, Wk, bk, Wv, bv, Wf, Wlo, bcat);
  qkv_kernel<<<dim3(1024), dim3(256), 0, stream>>>(x, Wf, Wlo, bcat, Qb, Kf, Vf);
  attn_kernel<<<dim3(1024), dim3(256), 0, stream>>>(Qb, Kf, Vf, x, gamma, out);
}